// Round 22
// baseline (233.015 us; speedup 1.0000x reference)
//
#include <hip/hip_runtime.h>
#include <hip/hip_bf16.h>
#include <cmath>

#define HH 128
#define WW 128
#define HWSZ (HH*WW)
#define BB 4
#define PH 130   // padded spatial dim

typedef __attribute__((ext_vector_type(8))) short short8;
typedef __attribute__((ext_vector_type(4))) short sh4;
typedef _Float16 half8 __attribute__((ext_vector_type(8)));
typedef _Float16 half4 __attribute__((ext_vector_type(4)));
typedef __attribute__((ext_vector_type(16))) float f32x16;

__device__ __forceinline__ ushort f16_rn(float f) {
    _Float16 h = (_Float16)f;
    return __builtin_bit_cast(ushort, h);
}
__device__ __forceinline__ float f16_f(ushort u) {
    return (float)__builtin_bit_cast(_Float16, u);
}
__device__ __forceinline__ float fast_tanh(float x) {
    const float e = __builtin_amdgcn_exp2f(x * 2.885390081777927f);   // e^(2x)
    return 1.f - 2.f * __builtin_amdgcn_rcpf(e + 1.f);
}
__device__ __forceinline__ float fast_sig(float x) {
    return __builtin_amdgcn_rcpf(1.f + __builtin_amdgcn_exp2f(-x * 1.4426950408889634f));
}

// ---------------------------------------------------------------------------
// Weight prep (conv0/1/2) -> per-tap fragment-ready fp16.
// ---------------------------------------------------------------------------
__global__ __launch_bounds__(256) void prep_wcm(const float* __restrict__ w,
                                                ushort* __restrict__ wOut,
                                                int ICREAL, int ICPAD) {
    const int ICSTEPS = ICPAD >> 4;
    int idx = blockIdx.x * 256 + threadIdx.x;
    if (idx >= 9 * ICSTEPS * 64 * 16) return;
    int j = idx & 7, lhi = (idx >> 3) & 1, oc = (idx >> 4) & 63, tk = idx >> 10;
    int tap = tk / ICSTEPS, ks = tk - tap * ICSTEPS;
    int ic = ks * 16 + lhi * 8 + j;
    float v = (ic < ICREAL) ? w[(size_t)oc * ICREAL * 9 + ic * 9 + tap] : 0.f;
    wOut[idx] = f16_rn(v);
}

// ---------------------------------------------------------------------------
// Weight prep (conv3, OCPAD=512) -> per-tap fragment-ready fp16.
// ---------------------------------------------------------------------------
__global__ __launch_bounds__(256) void prep_w3cm(const float* __restrict__ w,
                                                 ushort* __restrict__ wOut) {
    int idx = blockIdx.x * 256 + threadIdx.x;
    if (idx >= 36 * 512 * 16) return;
    int j = idx & 7, lhi = (idx >> 3) & 1, oc = (idx >> 4) & 511, tk = idx >> 13;
    int tap = tk >> 2, ks = tk & 3;
    int ic = ks * 16 + lhi * 8 + j;
    float v = (oc < 432) ? w[(size_t)oc * 576 + ic * 9 + tap] : 0.f;
    wOut[idx] = f16_rn(v);
}

// ---------------------------------------------------------------------------
// Deform weight prep -> fragment-ready fp16 (k-major kidx = k9*64 + c).
// ---------------------------------------------------------------------------
__global__ __launch_bounds__(256) void prep_wdf_k(const float* __restrict__ w,
                                                  ushort* __restrict__ whiF) {
    int idx = blockIdx.x * 256 + threadIdx.x;
    if (idx >= 64 * 576) return;
    int oc = idx / 576, rem = idx - oc * 576;
    int k9 = rem / 64, c = rem & 63;
    float v = w[(size_t)oc * 576 + c * 9 + k9];
    const int hv = c >> 5, r = c & 31;
    const int ks = r >> 4, lhi = (r >> 3) & 1, j = r & 7;
    const size_t dst = (size_t)((k9 * 2 + hv) * 2 + ks) * 1024 + oc * 16 + lhi * 8 + j;
    whiF[dst] = f16_rn(v);
}

// ---------------------------------------------------------------------------
// Zero the 1-px borders of a channel-minor padded buffer [BB][PH][PH][C].
// ---------------------------------------------------------------------------
__global__ __launch_bounds__(256) void zero_border(ushort* __restrict__ buf, int C) {
    int idx = blockIdx.x * 256 + threadIdx.x;
    if (idx >= BB * 4 * PH * C) return;
    int c = idx % C;
    int r = idx / C;
    int pos = r % PH;
    int zone = (r / PH) & 3;
    int b = r / (PH * 4);
    int y, x;
    if (zone == 0)      { y = 0;      x = pos; }
    else if (zone == 1) { y = PH - 1; x = pos; }
    else if (zone == 2) { y = pos;    x = 0; }
    else                { y = pos;    x = PH - 1; }
    buf[(((size_t)b * PH + y) * PH + x) * C + c] = 0;
}

// ---------------------------------------------------------------------------
// Concat {xfw,xcur,flow} -> channel-minor padded fp16 [b][130][130][144].
// ---------------------------------------------------------------------------
__global__ __launch_bounds__(256) void cvt_cm(const float* __restrict__ xfw,
                                              const float* __restrict__ xcur,
                                              const float* __restrict__ flow,
                                              ushort* __restrict__ out) {
    __shared__ ushort T[32][36];
    const int tid = threadIdx.x;
    const int b = blockIdx.x >> 7, y = blockIdx.x & 127;

    for (int c0 = 0; c0 < 144; c0 += 32) {
        for (int x0 = 0; x0 < 128; x0 += 32) {
            #pragma unroll
            for (int i = 0; i < 4; ++i) {
                const int cl = i * 8 + (tid >> 5);
                const int c = c0 + cl;
                const int x = x0 + (tid & 31);
                float v = 0.f;
                if (c < 64)       v = xfw [((size_t)b * 64 + c)       * HWSZ + y * WW + x];
                else if (c < 128) v = xcur[((size_t)b * 64 + c - 64)  * HWSZ + y * WW + x];
                else if (c < 130) v = flow[((size_t)b * 2  + c - 128) * HWSZ + y * WW + x];
                T[cl][tid & 31] = f16_rn(v);
            }
            __syncthreads();
            #pragma unroll
            for (int i = 0; i < 4; ++i) {
                const int xl = i * 8 + (tid >> 5);
                const int c = c0 + (tid & 31);
                if (c < 144)
                    out[(((size_t)b * PH + y + 1) * PH + x0 + xl + 1) * 144 + c] = T[tid & 31][xl];
            }
            __syncthreads();
        }
    }
}

// ---------------------------------------------------------------------------
// Pack x into gather-friendly fp16x4: xP[b][dg][pix].
// ---------------------------------------------------------------------------
__global__ __launch_bounds__(256) void pack_x_k(const float* __restrict__ x,
                                                sh4* __restrict__ xP) {
    int idx = blockIdx.x * 256 + threadIdx.x;
    if (idx >= BB * 16 * HWSZ) return;
    int b = idx / (16 * HWSZ);
    int rem = idx - b * 16 * HWSZ;
    int dg = rem / HWSZ, pix = rem - dg * HWSZ;
    const float* src = x + ((size_t)b * 64 + dg * 4) * HWSZ + pix;
    sh4 v;
    v[0] = (short)f16_rn(src[0]);
    v[1] = (short)f16_rn(src[HWSZ]);
    v[2] = (short)f16_rn(src[2 * HWSZ]);
    v[3] = (short)f16_rn(src[3 * HWSZ]);
    xP[idx] = v;
}

// ---------------------------------------------------------------------------
// conv0 (IC=144): zero-LDS channel-minor conv (halo too big to stage once).
// ---------------------------------------------------------------------------
template<int ICPAD, int ICSTEPS>
__global__ __launch_bounds__(512, 4) void conv_cm(
    const ushort* __restrict__ actIn, const ushort* __restrict__ wT,
    const float* __restrict__ bias, ushort* __restrict__ actOut)
{
    constexpr int SYI = PH * ICPAD;
    const int tid = threadIdx.x;
    const int id  = blockIdx.x;
    const int orig = (id & 7) * 64 + (id >> 3);    // 512 blocks, XCD-chunked
    const int b = orig >> 7, y = orig & 127;

    const int wave = tid >> 6, lane = tid & 63;
    const int wm = wave >> 2, wn = wave & 3;
    const int l31 = lane & 31, lhi = lane >> 5;

    f32x16 acc = {};

    const ushort* arow = actIn + ((size_t)b * PH + y) * SYI
                       + (wn * 32 + l31) * ICPAD + lhi * 8;
    const ushort* wb = wT + (wm * 32 + l31) * 16 + lhi * 8;

    #pragma unroll
    for (int tap = 0; tap < 9; ++tap) {
        const int ky = tap / 3, kx = tap % 3;
        #pragma unroll
        for (int ks = 0; ks < ICSTEPS; ++ks) {
            const half8 af = __builtin_bit_cast(half8,
                *(const short8*)&arow[ky * SYI + kx * ICPAD + ks * 16]);
            const half8 wf = __builtin_bit_cast(half8,
                *(const short8*)&wb[(size_t)(tap * ICSTEPS + ks) * 1024]);
            acc = __builtin_amdgcn_mfma_f32_32x32x16_f16(af, wf, acc, 0, 0, 0);
        }
    }

    const int oc = wm * 32 + l31;
    const float bi = bias[oc];
    ushort* ob = actOut + (((size_t)b * PH + y + 1) * PH + 1) * 64 + oc;
    #pragma unroll
    for (int r = 0; r < 16; ++r) {
        const int px = wn * 32 + (r & 3) + 8 * (r >> 2) + 4 * lhi;
        float v = acc[r] + bi;
        v = v >= 0.f ? v : 0.1f * v;
        ob[(size_t)px * 64] = f16_rn(v);
    }
}

// ---------------------------------------------------------------------------
// conv1/2 (IC=64): LDS-STAGED act (r18-proven swizzle, ported r21).
// ---------------------------------------------------------------------------
__global__ __launch_bounds__(512, 2) void conv_lds(
    const ushort* __restrict__ actIn, const ushort* __restrict__ wT,
    const float* __restrict__ bias, ushort* __restrict__ actOut)
{
    __shared__ ushort aS[3 * 130 * 64];   // 49,920 B

    const int tid = threadIdx.x;
    const int id  = blockIdx.x;
    const int orig = (id & 7) * 64 + (id >> 3);    // 512 blocks, XCD-chunked
    const int b = orig >> 7, y = orig & 127;

    const int wave = tid >> 6, lane = tid & 63;
    const int wm = wave >> 2, wn = wave & 3;
    const int l31 = lane & 31, lhi = lane >> 5;

    for (int i = tid; i < 3 * 130 * 8; i += 512) {
        const int seg = i & 7;
        const int px  = (i >> 3) % 130;
        const int row = (i >> 3) / 130;
        const ushort* src = actIn + (((size_t)b * PH + y + row) * PH + px) * 64 + seg * 8;
        const int d16 = (row * 130 + px) * 8 + (seg ^ (px & 7));
        *(short8*)&aS[d16 * 8] = *(const short8*)src;
    }
    __syncthreads();

    f32x16 acc = {};
    const ushort* wb = wT + (wm * 32 + l31) * 16 + lhi * 8;

    #pragma unroll
    for (int tap = 0; tap < 9; ++tap) {
        const int ky = tap / 3, kx = tap % 3;
        #pragma unroll
        for (int ks = 0; ks < 4; ++ks) {
            const int lpx = wn * 32 + l31 + kx;              // 0..129
            const int idx16 = (ky * 130 + lpx) * 8 + ((ks * 2 + lhi) ^ (lpx & 7));
            const half8 af = __builtin_bit_cast(half8,
                *(const short8*)&aS[idx16 * 8]);
            const half8 wf = __builtin_bit_cast(half8,
                *(const short8*)&wb[(size_t)(tap * 4 + ks) * 1024]);
            acc = __builtin_amdgcn_mfma_f32_32x32x16_f16(af, wf, acc, 0, 0, 0);
        }
    }

    const int oc = wm * 32 + l31;
    const float bi = bias[oc];
    ushort* ob = actOut + (((size_t)b * PH + y + 1) * PH + 1) * 64 + oc;
    #pragma unroll
    for (int r = 0; r < 16; ++r) {
        const int px = wn * 32 + (r & 3) + 8 * (r >> 2) + 4 * lhi;
        float v = acc[r] + bi;
        v = v >= 0.f ? v : 0.1f * v;
        ob[(size_t)px * 64] = f16_rn(v);
    }
}

// ---------------------------------------------------------------------------
// conv3 channel-minor v6: LDS-STAGED acts with XOR swizzle (proven r18).
// ---------------------------------------------------------------------------
__global__ __launch_bounds__(512, 4) void conv3_cm(
    const ushort* __restrict__ actIn, const ushort* __restrict__ wT3,
    const float* __restrict__ bias, uint* __restrict__ offP,
    ushort* __restrict__ mskP, const float* __restrict__ flow)
{
    __shared__ ushort aS[3 * 66 * 64];   // 25,344 B

    const int tid = threadIdx.x;
    const int id  = blockIdx.x;
    const int orig = (id & 7) * 128 + (id >> 3);   // 1024 blocks, bijective
    const int xhalf = orig & 1;
    const int rid = orig >> 1;
    const int b = rid >> 7, y = rid & 127;
    const int xb = xhalf * 64;

    const int wave = tid >> 6, lane = tid & 63;
    const int l31 = lane & 31, lhi = lane >> 5;
    const int o0 = wave * 64;

    for (int i = tid; i < 3 * 66 * 8; i += 512) {
        const int seg = i & 7;
        const int px  = (i >> 3) % 66;
        const int row = (i >> 3) / 66;
        const ushort* src = actIn + (((size_t)b * PH + y + row) * PH + xb + px) * 64 + seg * 8;
        const int d16 = (row * 66 + px) * 8 + (seg ^ (px & 7));
        *(short8*)&aS[d16 * 8] = *(const short8*)src;
    }
    __syncthreads();

    f32x16 acc[2][2] = {};
    const ushort* wb = wT3 + (o0 + l31) * 16 + lhi * 8;

    #pragma unroll
    for (int tap = 0; tap < 9; ++tap) {
        const int ky = tap / 3, kx = tap % 3;
        #pragma unroll
        for (int ks = 0; ks < 4; ++ks) {
            const half8 af0 = __builtin_bit_cast(half8,
                *(const short8*)&wb[(size_t)(tap * 4 + ks) * 8192]);
            const half8 af1 = __builtin_bit_cast(half8,
                *(const short8*)&wb[(size_t)(tap * 4 + ks) * 8192 + 512]);
            #pragma unroll
            for (int pg = 0; pg < 2; ++pg) {
                const int lpx = pg * 32 + l31 + kx;
                const int idx16 = (ky * 66 + lpx) * 8 + ((ks * 2 + lhi) ^ (lpx & 7));
                const half8 bf = __builtin_bit_cast(half8,
                    *(const short8*)&aS[idx16 * 8]);
                acc[0][pg] = __builtin_amdgcn_mfma_f32_32x32x16_f16(af0, bf, acc[0][pg], 0, 0, 0);
                acc[1][pg] = __builtin_amdgcn_mfma_f32_32x32x16_f16(af1, bf, acc[1][pg], 0, 0, 0);
            }
        }
    }

    uint*   offb = offP + (size_t)b * 144 * HWSZ;
    ushort* mskb = mskP + (size_t)b * 144 * HWSZ;
    #pragma unroll
    for (int pg = 0; pg < 2; ++pg) {
        const int px = xb + pg * 32 + l31;
        const size_t pixb = (size_t)y * WW + px;
        const float fl0 = flow[((size_t)b * 2)     * HWSZ + pixb];
        const float fl1 = flow[((size_t)b * 2 + 1) * HWSZ + pixb];
        #pragma unroll
        for (int mg = 0; mg < 2; ++mg) {
            #pragma unroll
            for (int t = 0; t < 8; ++t) {
                const int r0 = 2 * t;
                const int oc = o0 + mg * 32 + (r0 & 3) + 8 * (r0 >> 2) + 4 * lhi;
                const float vy = acc[mg][pg][r0]     + bias[oc < 432 ? oc : 0];
                const float vx = acc[mg][pg][r0 + 1] + bias[oc < 431 ? oc + 1 : 0];
                if (oc < 288) {
                    const float ry = 10.f * fast_tanh(vy) + fl1;
                    const float rx = 10.f * fast_tanh(vx) + fl0;
                    offb[(size_t)(oc >> 1) * HWSZ + pixb] =
                        (uint)f16_rn(ry) | ((uint)f16_rn(rx) << 16);
                } else if (oc < 432) {
                    mskb[(size_t)(oc - 288) * HWSZ + pixb] = f16_rn(fast_sig(vy));
                    mskb[(size_t)(oc - 287) * HWSZ + pixb] = f16_rn(fast_sig(vx));
                }
            }
        }
    }
}

// ---------------------------------------------------------------------------
// MFMA deformable conv v13: v11 structure + (a) packed-fp16 bilinear blend
// (v_pk_fma_f16: ~12 VALU/sample vs 36 in fp32) + (b) off/msk loads
// software-pipelined one k9-iteration ahead (static 4-elem register arrays;
// NOT the full unroll that regressed in r20). 8 waves/block, grid 1024.
// ---------------------------------------------------------------------------
__global__ __launch_bounds__(512, 4) void deform_v13(
    const sh4* __restrict__ xP, const uint* __restrict__ offP,
    const ushort* __restrict__ mskP, const ushort* __restrict__ wdfh,
    const float* __restrict__ bias, float* __restrict__ outp)
{
    __shared__ float red[2][2][64][33];   // 33,792 B

    const int tid = threadIdx.x;
    const int id  = blockIdx.x;
    const int orig = (id & 7) * 128 + (id >> 3);   // 1024 blocks, bijective
    const int x0 = (orig & 1) * 64;
    const int rl = orig >> 1;
    const int y = rl & 127, b = rl >> 7;

    const int wave = tid >> 6, lane = tid & 63;
    const int l31 = lane & 31, lhi = lane >> 5;
    const int pxh = wave >> 2;          // which 32-px half
    const int w4  = wave & 3;           // K-quadrant index
    const int k9h = w4 >> 1;
    const int hv  = w4 & 1;

    const int xp  = x0 + pxh * 32 + l31;
    const int pix = y * WW + xp;
    const uint*   offb = offP + (size_t)b * 144 * HWSZ;
    const ushort* mskb = mskP + (size_t)b * 144 * HWSZ;
    const float fy = (float)y, fx = (float)xp;

    f32x16 acc[2] = {};

    const int k9lo = k9h ? 5 : 0;
    const int k9hi = k9h ? 9 : 5;

    // prefetch buffers: q = ks*2 + d2
    uint  pOf[4];
    ushort pMk[4];
    #pragma unroll
    for (int q = 0; q < 4; ++q) {
        const int dg = hv * 8 + (q >> 1) * 4 + lhi * 2 + (q & 1);
        const int m  = dg * 9 + k9lo;
        pOf[q] = offb[(size_t)m * HWSZ + pix];
        pMk[q] = mskb[(size_t)m * HWSZ + pix];
    }

    for (int k9 = k9lo; k9 < k9hi; ++k9) {
        const float kyf = (float)(k9 / 3 - 1);
        const float kxf = (float)(k9 % 3 - 1);
        // consume current, issue next iteration's off/msk loads early
        uint  cOf[4];
        ushort cMk[4];
        #pragma unroll
        for (int q = 0; q < 4; ++q) { cOf[q] = pOf[q]; cMk[q] = pMk[q]; }
        if (k9 + 1 < k9hi) {
            #pragma unroll
            for (int q = 0; q < 4; ++q) {
                const int dg = hv * 8 + (q >> 1) * 4 + lhi * 2 + (q & 1);
                const int m  = dg * 9 + (k9 + 1);
                pOf[q] = offb[(size_t)m * HWSZ + pix];
                pMk[q] = mskb[(size_t)m * HWSZ + pix];
            }
        }
        #pragma unroll
        for (int ks = 0; ks < 2; ++ks) {
            short8 bfs;
            #pragma unroll
            for (int d2 = 0; d2 < 2; ++d2) {
                const int q  = ks * 2 + d2;
                const int dg = hv * 8 + ks * 4 + lhi * 2 + d2;
                const uint u = cOf[q];
                const float dy = f16_f((ushort)(u & 0xffffu));
                const float dx = f16_f((ushort)(u >> 16));
                const float mk = f16_f(cMk[q]);
                const float py = dy + kyf + fy;
                const float px = dx + kxf + fx;
                const float y0f = floorf(py), x0f = floorf(px);
                const float ly = py - y0f, lx = px - x0f;
                const int yi = (int)y0f, xi = (int)x0f;
                const float w00 = (1.f - ly) * (1.f - lx), w01 = (1.f - ly) * lx;
                const float w10 = ly * (1.f - lx),         w11 = ly * lx;
                const bool vy0 = (unsigned)yi < (unsigned)HH, vy1 = (unsigned)(yi + 1) < (unsigned)HH;
                const bool vx0 = (unsigned)xi < (unsigned)WW, vx1 = (unsigned)(xi + 1) < (unsigned)WW;
                const float f00 = (vy0 && vx0) ? w00 * mk : 0.f;
                const float f01 = (vy0 && vx1) ? w01 * mk : 0.f;
                const float f10 = (vy1 && vx0) ? w10 * mk : 0.f;
                const float f11 = (vy1 && vx1) ? w11 * mk : 0.f;
                const int cy0 = min(max(yi, 0), HH - 1), cy1 = min(max(yi + 1, 0), HH - 1);
                const int cx0 = min(max(xi, 0), WW - 1), cx1 = min(max(xi + 1, 0), WW - 1);
                const sh4* xg = xP + (size_t)(b * 16 + dg) * HWSZ;
                const half4 c00 = __builtin_bit_cast(half4, xg[cy0 * WW + cx0]);
                const half4 c01 = __builtin_bit_cast(half4, xg[cy0 * WW + cx1]);
                const half4 c10 = __builtin_bit_cast(half4, xg[cy1 * WW + cx0]);
                const half4 c11 = __builtin_bit_cast(half4, xg[cy1 * WW + cx1]);
                // packed fp16 bilinear blend (v_pk_fma_f16)
                const _Float16 h00 = (_Float16)f00, h01 = (_Float16)f01;
                const _Float16 h10 = (_Float16)f10, h11 = (_Float16)f11;
                half4 s = h00 * c00;
                s += h01 * c01;
                s += h10 * c10;
                s += h11 * c11;
                const sh4 sv = __builtin_bit_cast(sh4, s);
                bfs[d2 * 4 + 0] = sv[0];
                bfs[d2 * 4 + 1] = sv[1];
                bfs[d2 * 4 + 2] = sv[2];
                bfs[d2 * 4 + 3] = sv[3];
            }
            const half8 bf = __builtin_bit_cast(half8, bfs);
            const size_t abase = (size_t)((k9 * 2 + hv) * 2 + ks) * 1024 + l31 * 16 + lhi * 8;
            #pragma unroll
            for (int mg = 0; mg < 2; ++mg) {
                const half8 ah = __builtin_bit_cast(half8, *(const short8*)&wdfh[abase + mg * 512]);
                acc[mg] = __builtin_amdgcn_mfma_f32_32x32x16_f16(ah, bf, acc[mg], 0, 0, 0);
            }
        }
    }

    // ---- per-pxh 3-phase reduction across the 4 K-quadrant waves ----
    if (w4 >= 2) {
        #pragma unroll
        for (int mg = 0; mg < 2; ++mg)
            #pragma unroll
            for (int r = 0; r < 16; ++r)
                red[pxh][w4 - 2][lane][mg * 16 + r] = acc[mg][r];
    }
    __syncthreads();
    if (w4 < 2) {
        #pragma unroll
        for (int mg = 0; mg < 2; ++mg)
            #pragma unroll
            for (int r = 0; r < 16; ++r)
                acc[mg][r] += red[pxh][w4][lane][mg * 16 + r];
    }
    __syncthreads();
    if (w4 == 1) {
        #pragma unroll
        for (int mg = 0; mg < 2; ++mg)
            #pragma unroll
            for (int r = 0; r < 16; ++r)
                red[pxh][0][lane][mg * 16 + r] = acc[mg][r];
    }
    __syncthreads();
    if (w4 == 0) {
        #pragma unroll
        for (int mg = 0; mg < 2; ++mg)
            #pragma unroll
            for (int r = 0; r < 16; ++r) {
                const int oc = mg * 32 + (r & 3) + 8 * (r >> 2) + 4 * lhi;
                const float v = acc[mg][r] + red[pxh][0][lane][mg * 16 + r] + bias[oc];
                outp[(((size_t)b * 64 + oc) * HH + y) * WW + xp] = v;
            }
    }
}

// ---------------------------------------------------------------------------
extern "C" void kernel_launch(void* const* d_in, const int* in_sizes, int n_in,
                              void* d_out, int out_size, void* d_ws, size_t ws_size,
                              hipStream_t stream) {
    const float* x    = (const float*)d_in[0];
    const float* xfw  = (const float*)d_in[1];
    const float* xcur = (const float*)d_in[2];
    const float* flow = (const float*)d_in[3];
    const float* w0   = (const float*)d_in[4];
    const float* b0   = (const float*)d_in[5];
    const float* w1   = (const float*)d_in[6];
    const float* b1   = (const float*)d_in[7];
    const float* w2   = (const float*)d_in[8];
    const float* b2   = (const float*)d_in[9];
    const float* w3   = (const float*)d_in[10];
    const float* b3   = (const float*)d_in[11];
    const float* wdcn = (const float*)d_in[12];
    const float* bdcn = (const float*)d_in[13];
    float* out = (float*)d_out;

    // workspace layout (all 16B-aligned):
    char* p = (char*)d_ws;
    uint*   offP    = (uint*)p;                         p += (size_t)BB * 144 * HWSZ * 4;   // 37.7MB
    ushort* mskP    = (ushort*)p;                       p += (size_t)BB * 144 * HWSZ * 2;   // 18.9MB
    ushort* h0A     = (ushort*)p;                       p += (size_t)BB * PH * PH * 64 * 2; // 8.65MB
    ushort* h1A     = (ushort*)p;                       p += (size_t)BB * PH * PH * 64 * 2; // 8.65MB
    ushort* concatA = (ushort*)p;                       p += (size_t)BB * PH * PH * 144 * 2;// 19.5MB
    sh4*    xPh     = (sh4*)p;                          p += (size_t)BB * 16 * HWSZ * 8;    // 8.4MB
    ushort* wdh = (ushort*)p;                           p += 64 * 576 * 2;
    ushort* w0T = (ushort*)p;                           p += 9 * 9 * 64 * 16 * 2;
    ushort* w1T = (ushort*)p;                           p += 9 * 4 * 64 * 16 * 2;
    ushort* w2T = (ushort*)p;                           p += 9 * 4 * 64 * 16 * 2;
    ushort* w3T = (ushort*)p;                           p += 36 * 512 * 16 * 2;
    ushort* h2A = h0A;   // conv2 output reuses h0A (h0A dead after conv1)

    // zero only the 1-px borders (interiors fully written by producers)
    zero_border<<<dim3((BB * 4 * PH * 144 + 255) / 256), dim3(256), 0, stream>>>(concatA, 144);
    zero_border<<<dim3((BB * 4 * PH * 64 + 255) / 256),  dim3(256), 0, stream>>>(h0A, 64);
    zero_border<<<dim3((BB * 4 * PH * 64 + 255) / 256),  dim3(256), 0, stream>>>(h1A, 64);

    prep_wcm<<<dim3((9 * 9 * 64 * 16 + 255) / 256), dim3(256), 0, stream>>>(w0, w0T, 130, 144);
    prep_wcm<<<dim3((9 * 4 * 64 * 16 + 255) / 256), dim3(256), 0, stream>>>(w1, w1T, 64, 64);
    prep_wcm<<<dim3((9 * 4 * 64 * 16 + 255) / 256), dim3(256), 0, stream>>>(w2, w2T, 64, 64);
    prep_w3cm<<<dim3((36 * 512 * 16 + 255) / 256), dim3(256), 0, stream>>>(w3, w3T);
    prep_wdf_k<<<dim3((64 * 576 + 255) / 256), dim3(256), 0, stream>>>(wdcn, wdh);
    cvt_cm<<<dim3(BB * HH), dim3(256), 0, stream>>>(xfw, xcur, flow, concatA);
    pack_x_k<<<dim3((BB * 16 * HWSZ + 255) / 256), dim3(256), 0, stream>>>(x, xPh);

    conv_cm<144, 9><<<dim3(BB * HH), dim3(512), 0, stream>>>(concatA, w0T, b0, h0A);
    conv_lds<<<dim3(BB * HH), dim3(512), 0, stream>>>(h0A, w1T, b1, h1A);
    conv_lds<<<dim3(BB * HH), dim3(512), 0, stream>>>(h1A, w2T, b2, h2A);
    conv3_cm<<<dim3(BB * HH * 2), dim3(512), 0, stream>>>(h2A, w3T, b3, offP, mskP, flow);

    deform_v13<<<dim3(1024), dim3(512), 0, stream>>>(xPh, offP, mskP, wdh, bdcn, out);
}

// Round 23
// 210.058 us; speedup vs baseline: 1.1093x; 1.1093x over previous
//
#include <hip/hip_runtime.h>
#include <hip/hip_bf16.h>
#include <cmath>

#define HH 128
#define WW 128
#define HWSZ (HH*WW)
#define BB 4
#define PH 130   // padded spatial dim

typedef __attribute__((ext_vector_type(8))) short short8;
typedef __attribute__((ext_vector_type(4))) short sh4;
typedef _Float16 half8 __attribute__((ext_vector_type(8)));
typedef __attribute__((ext_vector_type(16))) float f32x16;

__device__ __forceinline__ ushort f16_rn(float f) {
    _Float16 h = (_Float16)f;
    return __builtin_bit_cast(ushort, h);
}
__device__ __forceinline__ float f16_f(ushort u) {
    return (float)__builtin_bit_cast(_Float16, u);
}
__device__ __forceinline__ float fast_tanh(float x) {
    const float e = __builtin_amdgcn_exp2f(x * 2.885390081777927f);   // e^(2x)
    return 1.f - 2.f * __builtin_amdgcn_rcpf(e + 1.f);
}
__device__ __forceinline__ float fast_sig(float x) {
    return __builtin_amdgcn_rcpf(1.f + __builtin_amdgcn_exp2f(-x * 1.4426950408889634f));
}

// ---------------------------------------------------------------------------
// Weight prep (conv0/1/2) -> per-tap fragment-ready fp16.
// ---------------------------------------------------------------------------
__global__ __launch_bounds__(256) void prep_wcm(const float* __restrict__ w,
                                                ushort* __restrict__ wOut,
                                                int ICREAL, int ICPAD) {
    const int ICSTEPS = ICPAD >> 4;
    int idx = blockIdx.x * 256 + threadIdx.x;
    if (idx >= 9 * ICSTEPS * 64 * 16) return;
    int j = idx & 7, lhi = (idx >> 3) & 1, oc = (idx >> 4) & 63, tk = idx >> 10;
    int tap = tk / ICSTEPS, ks = tk - tap * ICSTEPS;
    int ic = ks * 16 + lhi * 8 + j;
    float v = (ic < ICREAL) ? w[(size_t)oc * ICREAL * 9 + ic * 9 + tap] : 0.f;
    wOut[idx] = f16_rn(v);
}

// ---------------------------------------------------------------------------
// Weight prep (conv3, OCPAD=512) -> per-tap fragment-ready fp16.
// ---------------------------------------------------------------------------
__global__ __launch_bounds__(256) void prep_w3cm(const float* __restrict__ w,
                                                 ushort* __restrict__ wOut) {
    int idx = blockIdx.x * 256 + threadIdx.x;
    if (idx >= 36 * 512 * 16) return;
    int j = idx & 7, lhi = (idx >> 3) & 1, oc = (idx >> 4) & 511, tk = idx >> 13;
    int tap = tk >> 2, ks = tk & 3;
    int ic = ks * 16 + lhi * 8 + j;
    float v = (oc < 432) ? w[(size_t)oc * 576 + ic * 9 + tap] : 0.f;
    wOut[idx] = f16_rn(v);
}

// ---------------------------------------------------------------------------
// Deform weight prep -> fragment-ready fp16 (k-major kidx = k9*64 + c).
// ---------------------------------------------------------------------------
__global__ __launch_bounds__(256) void prep_wdf_k(const float* __restrict__ w,
                                                  ushort* __restrict__ whiF) {
    int idx = blockIdx.x * 256 + threadIdx.x;
    if (idx >= 64 * 576) return;
    int oc = idx / 576, rem = idx - oc * 576;
    int k9 = rem / 64, c = rem & 63;
    float v = w[(size_t)oc * 576 + c * 9 + k9];
    const int hv = c >> 5, r = c & 31;
    const int ks = r >> 4, lhi = (r >> 3) & 1, j = r & 7;
    const size_t dst = (size_t)((k9 * 2 + hv) * 2 + ks) * 1024 + oc * 16 + lhi * 8 + j;
    whiF[dst] = f16_rn(v);
}

// ---------------------------------------------------------------------------
// Zero the 1-px borders of a channel-minor padded buffer [BB][PH][PH][C].
// ---------------------------------------------------------------------------
__global__ __launch_bounds__(256) void zero_border(ushort* __restrict__ buf, int C) {
    int idx = blockIdx.x * 256 + threadIdx.x;
    if (idx >= BB * 4 * PH * C) return;
    int c = idx % C;
    int r = idx / C;
    int pos = r % PH;
    int zone = (r / PH) & 3;
    int b = r / (PH * 4);
    int y, x;
    if (zone == 0)      { y = 0;      x = pos; }
    else if (zone == 1) { y = PH - 1; x = pos; }
    else if (zone == 2) { y = pos;    x = 0; }
    else                { y = pos;    x = PH - 1; }
    buf[(((size_t)b * PH + y) * PH + x) * C + c] = 0;
}

// ---------------------------------------------------------------------------
// Concat {xfw,xcur,flow} -> channel-minor padded fp16 [b][130][130][144].
// ---------------------------------------------------------------------------
__global__ __launch_bounds__(256) void cvt_cm(const float* __restrict__ xfw,
                                              const float* __restrict__ xcur,
                                              const float* __restrict__ flow,
                                              ushort* __restrict__ out) {
    __shared__ ushort T[32][36];
    const int tid = threadIdx.x;
    const int b = blockIdx.x >> 7, y = blockIdx.x & 127;

    for (int c0 = 0; c0 < 144; c0 += 32) {
        for (int x0 = 0; x0 < 128; x0 += 32) {
            #pragma unroll
            for (int i = 0; i < 4; ++i) {
                const int cl = i * 8 + (tid >> 5);
                const int c = c0 + cl;
                const int x = x0 + (tid & 31);
                float v = 0.f;
                if (c < 64)       v = xfw [((size_t)b * 64 + c)       * HWSZ + y * WW + x];
                else if (c < 128) v = xcur[((size_t)b * 64 + c - 64)  * HWSZ + y * WW + x];
                else if (c < 130) v = flow[((size_t)b * 2  + c - 128) * HWSZ + y * WW + x];
                T[cl][tid & 31] = f16_rn(v);
            }
            __syncthreads();
            #pragma unroll
            for (int i = 0; i < 4; ++i) {
                const int xl = i * 8 + (tid >> 5);
                const int c = c0 + (tid & 31);
                if (c < 144)
                    out[(((size_t)b * PH + y + 1) * PH + x0 + xl + 1) * 144 + c] = T[tid & 31][xl];
            }
            __syncthreads();
        }
    }
}

// ---------------------------------------------------------------------------
// Pack x into gather-friendly fp16x4: xP[b][dg][pix].
// ---------------------------------------------------------------------------
__global__ __launch_bounds__(256) void pack_x_k(const float* __restrict__ x,
                                                sh4* __restrict__ xP) {
    int idx = blockIdx.x * 256 + threadIdx.x;
    if (idx >= BB * 16 * HWSZ) return;
    int b = idx / (16 * HWSZ);
    int rem = idx - b * 16 * HWSZ;
    int dg = rem / HWSZ, pix = rem - dg * HWSZ;
    const float* src = x + ((size_t)b * 64 + dg * 4) * HWSZ + pix;
    sh4 v;
    v[0] = (short)f16_rn(src[0]);
    v[1] = (short)f16_rn(src[HWSZ]);
    v[2] = (short)f16_rn(src[2 * HWSZ]);
    v[3] = (short)f16_rn(src[3 * HWSZ]);
    xP[idx] = v;
}

// ---------------------------------------------------------------------------
// conv0 (IC=144) LDS-STAGED, seg-major layout [18 segs][3 rows][66 px] of
// 16B granules: reads are lanes-at-consecutive-16B (bank-minimal, no
// swizzle needed since 18 segs isn't po2); staging is memory-order
// coalesced. Block = half-row (64 px) x 64 oc, 256 thr = 4 waves
// (2 oc-half x 2 px-half); LDS 57 KB (2 blocks/CU); grid 1024.
// ---------------------------------------------------------------------------
__global__ __launch_bounds__(256, 2) void conv0_lds(
    const ushort* __restrict__ actIn, const ushort* __restrict__ wT,
    const float* __restrict__ bias, ushort* __restrict__ actOut)
{
    __shared__ ushort aS[18 * 3 * 66 * 8];   // 57,024 B

    const int tid = threadIdx.x;
    const int id  = blockIdx.x;
    const int orig = (id & 7) * 128 + (id >> 3);   // 1024 blocks, bijective
    const int xhalf = orig & 1;
    const int rid = orig >> 1;
    const int b = rid >> 7, y = rid & 127;
    const int xb = xhalf * 64;

    const int wave = tid >> 6, lane = tid & 63;
    const int wm = wave >> 1, wn = wave & 1;
    const int l31 = lane & 31, lhi = lane >> 5;

    // ---- stage: rows y..y+2 (padded), px xb..xb+65, 144 ch (18 segs) ----
    for (int i = tid; i < 18 * 3 * 66; i += 256) {
        const int seg = i % 18;
        const int rp  = i / 18;
        const int px  = rp % 66;
        const int row = rp / 66;
        const ushort* src = actIn + (((size_t)b * PH + y + row) * PH + xb + px) * 144 + seg * 8;
        const int g = (seg * 3 + row) * 66 + px;
        *(short8*)&aS[g * 8] = *(const short8*)src;
    }
    __syncthreads();

    f32x16 acc = {};
    const ushort* wb = wT + (wm * 32 + l31) * 16 + lhi * 8;

    #pragma unroll
    for (int tap = 0; tap < 9; ++tap) {
        const int ky = tap / 3, kx = tap % 3;
        #pragma unroll
        for (int ks = 0; ks < 9; ++ks) {
            const int g = ((ks * 2 + lhi) * 3 + ky) * 66 + (wn * 32 + l31 + kx);
            const half8 af = __builtin_bit_cast(half8,
                *(const short8*)&aS[g * 8]);
            const half8 wf = __builtin_bit_cast(half8,
                *(const short8*)&wb[(size_t)(tap * 9 + ks) * 1024]);
            acc = __builtin_amdgcn_mfma_f32_32x32x16_f16(af, wf, acc, 0, 0, 0);
        }
    }

    const int oc = wm * 32 + l31;
    const float bi = bias[oc];
    ushort* ob = actOut + (((size_t)b * PH + y + 1) * PH + 1) * 64 + oc;
    #pragma unroll
    for (int r = 0; r < 16; ++r) {
        const int px = xb + wn * 32 + (r & 3) + 8 * (r >> 2) + 4 * lhi;
        float v = acc[r] + bi;
        v = v >= 0.f ? v : 0.1f * v;
        ob[(size_t)px * 64] = f16_rn(v);
    }
}

// ---------------------------------------------------------------------------
// conv1/2 (IC=64): LDS-STAGED act (r18-proven swizzle, ported r21).
// ---------------------------------------------------------------------------
__global__ __launch_bounds__(512, 2) void conv_lds(
    const ushort* __restrict__ actIn, const ushort* __restrict__ wT,
    const float* __restrict__ bias, ushort* __restrict__ actOut)
{
    __shared__ ushort aS[3 * 130 * 64];   // 49,920 B

    const int tid = threadIdx.x;
    const int id  = blockIdx.x;
    const int orig = (id & 7) * 64 + (id >> 3);    // 512 blocks, XCD-chunked
    const int b = orig >> 7, y = orig & 127;

    const int wave = tid >> 6, lane = tid & 63;
    const int wm = wave >> 2, wn = wave & 3;
    const int l31 = lane & 31, lhi = lane >> 5;

    for (int i = tid; i < 3 * 130 * 8; i += 512) {
        const int seg = i & 7;
        const int px  = (i >> 3) % 130;
        const int row = (i >> 3) / 130;
        const ushort* src = actIn + (((size_t)b * PH + y + row) * PH + px) * 64 + seg * 8;
        const int d16 = (row * 130 + px) * 8 + (seg ^ (px & 7));
        *(short8*)&aS[d16 * 8] = *(const short8*)src;
    }
    __syncthreads();

    f32x16 acc = {};
    const ushort* wb = wT + (wm * 32 + l31) * 16 + lhi * 8;

    #pragma unroll
    for (int tap = 0; tap < 9; ++tap) {
        const int ky = tap / 3, kx = tap % 3;
        #pragma unroll
        for (int ks = 0; ks < 4; ++ks) {
            const int lpx = wn * 32 + l31 + kx;              // 0..129
            const int idx16 = (ky * 130 + lpx) * 8 + ((ks * 2 + lhi) ^ (lpx & 7));
            const half8 af = __builtin_bit_cast(half8,
                *(const short8*)&aS[idx16 * 8]);
            const half8 wf = __builtin_bit_cast(half8,
                *(const short8*)&wb[(size_t)(tap * 4 + ks) * 1024]);
            acc = __builtin_amdgcn_mfma_f32_32x32x16_f16(af, wf, acc, 0, 0, 0);
        }
    }

    const int oc = wm * 32 + l31;
    const float bi = bias[oc];
    ushort* ob = actOut + (((size_t)b * PH + y + 1) * PH + 1) * 64 + oc;
    #pragma unroll
    for (int r = 0; r < 16; ++r) {
        const int px = wn * 32 + (r & 3) + 8 * (r >> 2) + 4 * lhi;
        float v = acc[r] + bi;
        v = v >= 0.f ? v : 0.1f * v;
        ob[(size_t)px * 64] = f16_rn(v);
    }
}

// ---------------------------------------------------------------------------
// conv3 channel-minor v6: LDS-STAGED acts with XOR swizzle (proven r18).
// ---------------------------------------------------------------------------
__global__ __launch_bounds__(512, 4) void conv3_cm(
    const ushort* __restrict__ actIn, const ushort* __restrict__ wT3,
    const float* __restrict__ bias, uint* __restrict__ offP,
    ushort* __restrict__ mskP, const float* __restrict__ flow)
{
    __shared__ ushort aS[3 * 66 * 64];   // 25,344 B

    const int tid = threadIdx.x;
    const int id  = blockIdx.x;
    const int orig = (id & 7) * 128 + (id >> 3);   // 1024 blocks, bijective
    const int xhalf = orig & 1;
    const int rid = orig >> 1;
    const int b = rid >> 7, y = rid & 127;
    const int xb = xhalf * 64;

    const int wave = tid >> 6, lane = tid & 63;
    const int l31 = lane & 31, lhi = lane >> 5;
    const int o0 = wave * 64;

    for (int i = tid; i < 3 * 66 * 8; i += 512) {
        const int seg = i & 7;
        const int px  = (i >> 3) % 66;
        const int row = (i >> 3) / 66;
        const ushort* src = actIn + (((size_t)b * PH + y + row) * PH + xb + px) * 64 + seg * 8;
        const int d16 = (row * 66 + px) * 8 + (seg ^ (px & 7));
        *(short8*)&aS[d16 * 8] = *(const short8*)src;
    }
    __syncthreads();

    f32x16 acc[2][2] = {};
    const ushort* wb = wT3 + (o0 + l31) * 16 + lhi * 8;

    #pragma unroll
    for (int tap = 0; tap < 9; ++tap) {
        const int ky = tap / 3, kx = tap % 3;
        #pragma unroll
        for (int ks = 0; ks < 4; ++ks) {
            const half8 af0 = __builtin_bit_cast(half8,
                *(const short8*)&wb[(size_t)(tap * 4 + ks) * 8192]);
            const half8 af1 = __builtin_bit_cast(half8,
                *(const short8*)&wb[(size_t)(tap * 4 + ks) * 8192 + 512]);
            #pragma unroll
            for (int pg = 0; pg < 2; ++pg) {
                const int lpx = pg * 32 + l31 + kx;
                const int idx16 = (ky * 66 + lpx) * 8 + ((ks * 2 + lhi) ^ (lpx & 7));
                const half8 bf = __builtin_bit_cast(half8,
                    *(const short8*)&aS[idx16 * 8]);
                acc[0][pg] = __builtin_amdgcn_mfma_f32_32x32x16_f16(af0, bf, acc[0][pg], 0, 0, 0);
                acc[1][pg] = __builtin_amdgcn_mfma_f32_32x32x16_f16(af1, bf, acc[1][pg], 0, 0, 0);
            }
        }
    }

    uint*   offb = offP + (size_t)b * 144 * HWSZ;
    ushort* mskb = mskP + (size_t)b * 144 * HWSZ;
    #pragma unroll
    for (int pg = 0; pg < 2; ++pg) {
        const int px = xb + pg * 32 + l31;
        const size_t pixb = (size_t)y * WW + px;
        const float fl0 = flow[((size_t)b * 2)     * HWSZ + pixb];
        const float fl1 = flow[((size_t)b * 2 + 1) * HWSZ + pixb];
        #pragma unroll
        for (int mg = 0; mg < 2; ++mg) {
            #pragma unroll
            for (int t = 0; t < 8; ++t) {
                const int r0 = 2 * t;
                const int oc = o0 + mg * 32 + (r0 & 3) + 8 * (r0 >> 2) + 4 * lhi;
                const float vy = acc[mg][pg][r0]     + bias[oc < 432 ? oc : 0];
                const float vx = acc[mg][pg][r0 + 1] + bias[oc < 431 ? oc + 1 : 0];
                if (oc < 288) {
                    const float ry = 10.f * fast_tanh(vy) + fl1;
                    const float rx = 10.f * fast_tanh(vx) + fl0;
                    offb[(size_t)(oc >> 1) * HWSZ + pixb] =
                        (uint)f16_rn(ry) | ((uint)f16_rn(rx) << 16);
                } else if (oc < 432) {
                    mskb[(size_t)(oc - 288) * HWSZ + pixb] = f16_rn(fast_sig(vy));
                    mskb[(size_t)(oc - 287) * HWSZ + pixb] = f16_rn(fast_sig(vx));
                }
            }
        }
    }
}

// ---------------------------------------------------------------------------
// MFMA deformable conv v11 (proven r19/r21, 78us): 8-wave blocks; wave =
// (pxh, k9h, hv); runtime k9 loop. Per-pxh 3-phase LDS reduction.
// ---------------------------------------------------------------------------
__global__ __launch_bounds__(512, 4) void deform_v11(
    const sh4* __restrict__ xP, const uint* __restrict__ offP,
    const ushort* __restrict__ mskP, const ushort* __restrict__ wdfh,
    const float* __restrict__ bias, float* __restrict__ outp)
{
    __shared__ float red[2][2][64][33];   // 33,792 B

    const int tid = threadIdx.x;
    const int id  = blockIdx.x;
    const int orig = (id & 7) * 128 + (id >> 3);   // 1024 blocks, bijective
    const int x0 = (orig & 1) * 64;
    const int rl = orig >> 1;
    const int y = rl & 127, b = rl >> 7;

    const int wave = tid >> 6, lane = tid & 63;
    const int l31 = lane & 31, lhi = lane >> 5;
    const int pxh = wave >> 2;          // which 32-px half
    const int w4  = wave & 3;           // K-quadrant index
    const int k9h = w4 >> 1;
    const int hv  = w4 & 1;

    const int xp  = x0 + pxh * 32 + l31;
    const int pix = y * WW + xp;
    const uint*   offb = offP + (size_t)b * 144 * HWSZ;
    const ushort* mskb = mskP + (size_t)b * 144 * HWSZ;
    const float fy = (float)y, fx = (float)xp;

    f32x16 acc[2] = {};

    const int k9lo = k9h ? 5 : 0;
    const int k9hi = k9h ? 9 : 5;
    for (int k9 = k9lo; k9 < k9hi; ++k9) {
        const float kyf = (float)(k9 / 3 - 1);
        const float kxf = (float)(k9 % 3 - 1);
        #pragma unroll
        for (int ks = 0; ks < 2; ++ks) {
            short8 bfs;
            #pragma unroll
            for (int d2 = 0; d2 < 2; ++d2) {
                const int dg = hv * 8 + ks * 4 + lhi * 2 + d2;
                const int m  = dg * 9 + k9;
                const uint u = offb[(size_t)m * HWSZ + pix];
                const float dy = f16_f((ushort)(u & 0xffffu));
                const float dx = f16_f((ushort)(u >> 16));
                const float mk = f16_f(mskb[(size_t)m * HWSZ + pix]);
                const float py = dy + kyf + fy;
                const float px = dx + kxf + fx;
                const float y0f = floorf(py), x0f = floorf(px);
                const float ly = py - y0f, lx = px - x0f;
                const int yi = (int)y0f, xi = (int)x0f;
                const float w00 = (1.f - ly) * (1.f - lx), w01 = (1.f - ly) * lx;
                const float w10 = ly * (1.f - lx),         w11 = ly * lx;
                const bool vy0 = (unsigned)yi < (unsigned)HH, vy1 = (unsigned)(yi + 1) < (unsigned)HH;
                const bool vx0 = (unsigned)xi < (unsigned)WW, vx1 = (unsigned)(xi + 1) < (unsigned)WW;
                const float f00 = (vy0 && vx0) ? w00 * mk : 0.f;
                const float f01 = (vy0 && vx1) ? w01 * mk : 0.f;
                const float f10 = (vy1 && vx0) ? w10 * mk : 0.f;
                const float f11 = (vy1 && vx1) ? w11 * mk : 0.f;
                const int cy0 = min(max(yi, 0), HH - 1), cy1 = min(max(yi + 1, 0), HH - 1);
                const int cx0 = min(max(xi, 0), WW - 1), cx1 = min(max(xi + 1, 0), WW - 1);
                const sh4* xg = xP + (size_t)(b * 16 + dg) * HWSZ;
                const sh4 c00 = xg[cy0 * WW + cx0], c01 = xg[cy0 * WW + cx1];
                const sh4 c10 = xg[cy1 * WW + cx0], c11 = xg[cy1 * WW + cx1];
                #pragma unroll
                for (int n = 0; n < 4; ++n) {
                    const float s = f00 * f16_f((ushort)c00[n]) + f01 * f16_f((ushort)c01[n])
                                  + f10 * f16_f((ushort)c10[n]) + f11 * f16_f((ushort)c11[n]);
                    bfs[d2 * 4 + n] = (short)f16_rn(s);
                }
            }
            const half8 bf = __builtin_bit_cast(half8, bfs);
            const size_t abase = (size_t)((k9 * 2 + hv) * 2 + ks) * 1024 + l31 * 16 + lhi * 8;
            #pragma unroll
            for (int mg = 0; mg < 2; ++mg) {
                const half8 ah = __builtin_bit_cast(half8, *(const short8*)&wdfh[abase + mg * 512]);
                acc[mg] = __builtin_amdgcn_mfma_f32_32x32x16_f16(ah, bf, acc[mg], 0, 0, 0);
            }
        }
    }

    // ---- per-pxh 3-phase reduction across the 4 K-quadrant waves ----
    if (w4 >= 2) {
        #pragma unroll
        for (int mg = 0; mg < 2; ++mg)
            #pragma unroll
            for (int r = 0; r < 16; ++r)
                red[pxh][w4 - 2][lane][mg * 16 + r] = acc[mg][r];
    }
    __syncthreads();
    if (w4 < 2) {
        #pragma unroll
        for (int mg = 0; mg < 2; ++mg)
            #pragma unroll
            for (int r = 0; r < 16; ++r)
                acc[mg][r] += red[pxh][w4][lane][mg * 16 + r];
    }
    __syncthreads();
    if (w4 == 1) {
        #pragma unroll
        for (int mg = 0; mg < 2; ++mg)
            #pragma unroll
            for (int r = 0; r < 16; ++r)
                red[pxh][0][lane][mg * 16 + r] = acc[mg][r];
    }
    __syncthreads();
    if (w4 == 0) {
        #pragma unroll
        for (int mg = 0; mg < 2; ++mg)
            #pragma unroll
            for (int r = 0; r < 16; ++r) {
                const int oc = mg * 32 + (r & 3) + 8 * (r >> 2) + 4 * lhi;
                const float v = acc[mg][r] + red[pxh][0][lane][mg * 16 + r] + bias[oc];
                outp[(((size_t)b * 64 + oc) * HH + y) * WW + xp] = v;
            }
    }
}

// ---------------------------------------------------------------------------
extern "C" void kernel_launch(void* const* d_in, const int* in_sizes, int n_in,
                              void* d_out, int out_size, void* d_ws, size_t ws_size,
                              hipStream_t stream) {
    const float* x    = (const float*)d_in[0];
    const float* xfw  = (const float*)d_in[1];
    const float* xcur = (const float*)d_in[2];
    const float* flow = (const float*)d_in[3];
    const float* w0   = (const float*)d_in[4];
    const float* b0   = (const float*)d_in[5];
    const float* w1   = (const float*)d_in[6];
    const float* b1   = (const float*)d_in[7];
    const float* w2   = (const float*)d_in[8];
    const float* b2   = (const float*)d_in[9];
    const float* w3   = (const float*)d_in[10];
    const float* b3   = (const float*)d_in[11];
    const float* wdcn = (const float*)d_in[12];
    const float* bdcn = (const float*)d_in[13];
    float* out = (float*)d_out;

    // workspace layout (all 16B-aligned):
    char* p = (char*)d_ws;
    uint*   offP    = (uint*)p;                         p += (size_t)BB * 144 * HWSZ * 4;   // 37.7MB
    ushort* mskP    = (ushort*)p;                       p += (size_t)BB * 144 * HWSZ * 2;   // 18.9MB
    ushort* h0A     = (ushort*)p;                       p += (size_t)BB * PH * PH * 64 * 2; // 8.65MB
    ushort* h1A     = (ushort*)p;                       p += (size_t)BB * PH * PH * 64 * 2; // 8.65MB
    ushort* concatA = (ushort*)p;                       p += (size_t)BB * PH * PH * 144 * 2;// 19.5MB
    sh4*    xPh     = (sh4*)p;                          p += (size_t)BB * 16 * HWSZ * 8;    // 8.4MB
    ushort* wdh = (ushort*)p;                           p += 64 * 576 * 2;
    ushort* w0T = (ushort*)p;                           p += 9 * 9 * 64 * 16 * 2;
    ushort* w1T = (ushort*)p;                           p += 9 * 4 * 64 * 16 * 2;
    ushort* w2T = (ushort*)p;                           p += 9 * 4 * 64 * 16 * 2;
    ushort* w3T = (ushort*)p;                           p += 36 * 512 * 16 * 2;
    ushort* h2A = h0A;   // conv2 output reuses h0A (h0A dead after conv1)

    // zero only the 1-px borders (interiors fully written by producers)
    zero_border<<<dim3((BB * 4 * PH * 144 + 255) / 256), dim3(256), 0, stream>>>(concatA, 144);
    zero_border<<<dim3((BB * 4 * PH * 64 + 255) / 256),  dim3(256), 0, stream>>>(h0A, 64);
    zero_border<<<dim3((BB * 4 * PH * 64 + 255) / 256),  dim3(256), 0, stream>>>(h1A, 64);

    prep_wcm<<<dim3((9 * 9 * 64 * 16 + 255) / 256), dim3(256), 0, stream>>>(w0, w0T, 130, 144);
    prep_wcm<<<dim3((9 * 4 * 64 * 16 + 255) / 256), dim3(256), 0, stream>>>(w1, w1T, 64, 64);
    prep_wcm<<<dim3((9 * 4 * 64 * 16 + 255) / 256), dim3(256), 0, stream>>>(w2, w2T, 64, 64);
    prep_w3cm<<<dim3((36 * 512 * 16 + 255) / 256), dim3(256), 0, stream>>>(w3, w3T);
    prep_wdf_k<<<dim3((64 * 576 + 255) / 256), dim3(256), 0, stream>>>(wdcn, wdh);
    cvt_cm<<<dim3(BB * HH), dim3(256), 0, stream>>>(xfw, xcur, flow, concatA);
    pack_x_k<<<dim3((BB * 16 * HWSZ + 255) / 256), dim3(256), 0, stream>>>(x, xPh);

    conv0_lds<<<dim3(BB * HH * 2), dim3(256), 0, stream>>>(concatA, w0T, b0, h0A);
    conv_lds<<<dim3(BB * HH), dim3(512), 0, stream>>>(h0A, w1T, b1, h1A);
    conv_lds<<<dim3(BB * HH), dim3(512), 0, stream>>>(h1A, w2T, b2, h2A);
    conv3_cm<<<dim3(BB * HH * 2), dim3(512), 0, stream>>>(h2A, w3T, b3, offP, mskP, flow);

    deform_v11<<<dim3(1024), dim3(512), 0, stream>>>(xPh, offP, mskP, wdh, bdcn, out);
}

// Round 24
// 207.019 us; speedup vs baseline: 1.1256x; 1.0147x over previous
//
#include <hip/hip_runtime.h>
#include <hip/hip_bf16.h>
#include <cmath>

#define HH 128
#define WW 128
#define HWSZ (HH*WW)
#define BB 4
#define PH 130   // padded spatial dim

typedef __attribute__((ext_vector_type(8))) short short8;
typedef __attribute__((ext_vector_type(8), aligned(8))) short short8u; // 8B-aligned 16B pair
typedef __attribute__((ext_vector_type(4))) short sh4;
typedef _Float16 half8 __attribute__((ext_vector_type(8)));
typedef __attribute__((ext_vector_type(16))) float f32x16;

__device__ __forceinline__ ushort f16_rn(float f) {
    _Float16 h = (_Float16)f;
    return __builtin_bit_cast(ushort, h);
}
__device__ __forceinline__ float f16_f(ushort u) {
    return (float)__builtin_bit_cast(_Float16, u);
}
__device__ __forceinline__ float fast_tanh(float x) {
    const float e = __builtin_amdgcn_exp2f(x * 2.885390081777927f);   // e^(2x)
    return 1.f - 2.f * __builtin_amdgcn_rcpf(e + 1.f);
}
__device__ __forceinline__ float fast_sig(float x) {
    return __builtin_amdgcn_rcpf(1.f + __builtin_amdgcn_exp2f(-x * 1.4426950408889634f));
}

// ---------------------------------------------------------------------------
// Weight prep (conv0/1/2) -> per-tap fragment-ready fp16.
// ---------------------------------------------------------------------------
__global__ __launch_bounds__(256) void prep_wcm(const float* __restrict__ w,
                                                ushort* __restrict__ wOut,
                                                int ICREAL, int ICPAD) {
    const int ICSTEPS = ICPAD >> 4;
    int idx = blockIdx.x * 256 + threadIdx.x;
    if (idx >= 9 * ICSTEPS * 64 * 16) return;
    int j = idx & 7, lhi = (idx >> 3) & 1, oc = (idx >> 4) & 63, tk = idx >> 10;
    int tap = tk / ICSTEPS, ks = tk - tap * ICSTEPS;
    int ic = ks * 16 + lhi * 8 + j;
    float v = (ic < ICREAL) ? w[(size_t)oc * ICREAL * 9 + ic * 9 + tap] : 0.f;
    wOut[idx] = f16_rn(v);
}

// ---------------------------------------------------------------------------
// Weight prep (conv3, OCPAD=512) -> per-tap fragment-ready fp16.
// ---------------------------------------------------------------------------
__global__ __launch_bounds__(256) void prep_w3cm(const float* __restrict__ w,
                                                 ushort* __restrict__ wOut) {
    int idx = blockIdx.x * 256 + threadIdx.x;
    if (idx >= 36 * 512 * 16) return;
    int j = idx & 7, lhi = (idx >> 3) & 1, oc = (idx >> 4) & 511, tk = idx >> 13;
    int tap = tk >> 2, ks = tk & 3;
    int ic = ks * 16 + lhi * 8 + j;
    float v = (oc < 432) ? w[(size_t)oc * 576 + ic * 9 + tap] : 0.f;
    wOut[idx] = f16_rn(v);
}

// ---------------------------------------------------------------------------
// Deform weight prep -> fragment-ready fp16 (k-major kidx = k9*64 + c).
// ---------------------------------------------------------------------------
__global__ __launch_bounds__(256) void prep_wdf_k(const float* __restrict__ w,
                                                  ushort* __restrict__ whiF) {
    int idx = blockIdx.x * 256 + threadIdx.x;
    if (idx >= 64 * 576) return;
    int oc = idx / 576, rem = idx - oc * 576;
    int k9 = rem / 64, c = rem & 63;
    float v = w[(size_t)oc * 576 + c * 9 + k9];
    const int hv = c >> 5, r = c & 31;
    const int ks = r >> 4, lhi = (r >> 3) & 1, j = r & 7;
    const size_t dst = (size_t)((k9 * 2 + hv) * 2 + ks) * 1024 + oc * 16 + lhi * 8 + j;
    whiF[dst] = f16_rn(v);
}

// ---------------------------------------------------------------------------
// Zero the 1-px borders of a channel-minor padded buffer [BB][PH][PH][C].
// ---------------------------------------------------------------------------
__global__ __launch_bounds__(256) void zero_border(ushort* __restrict__ buf, int C) {
    int idx = blockIdx.x * 256 + threadIdx.x;
    if (idx >= BB * 4 * PH * C) return;
    int c = idx % C;
    int r = idx / C;
    int pos = r % PH;
    int zone = (r / PH) & 3;
    int b = r / (PH * 4);
    int y, x;
    if (zone == 0)      { y = 0;      x = pos; }
    else if (zone == 1) { y = PH - 1; x = pos; }
    else if (zone == 2) { y = pos;    x = 0; }
    else                { y = pos;    x = PH - 1; }
    buf[(((size_t)b * PH + y) * PH + x) * C + c] = 0;
}

// ---------------------------------------------------------------------------
// Concat {xfw,xcur,flow} -> channel-minor padded fp16 [b][130][130][144].
// ---------------------------------------------------------------------------
__global__ __launch_bounds__(256) void cvt_cm(const float* __restrict__ xfw,
                                              const float* __restrict__ xcur,
                                              const float* __restrict__ flow,
                                              ushort* __restrict__ out) {
    __shared__ ushort T[32][36];
    const int tid = threadIdx.x;
    const int b = blockIdx.x >> 7, y = blockIdx.x & 127;

    for (int c0 = 0; c0 < 144; c0 += 32) {
        for (int x0 = 0; x0 < 128; x0 += 32) {
            #pragma unroll
            for (int i = 0; i < 4; ++i) {
                const int cl = i * 8 + (tid >> 5);
                const int c = c0 + cl;
                const int x = x0 + (tid & 31);
                float v = 0.f;
                if (c < 64)       v = xfw [((size_t)b * 64 + c)       * HWSZ + y * WW + x];
                else if (c < 128) v = xcur[((size_t)b * 64 + c - 64)  * HWSZ + y * WW + x];
                else if (c < 130) v = flow[((size_t)b * 2  + c - 128) * HWSZ + y * WW + x];
                T[cl][tid & 31] = f16_rn(v);
            }
            __syncthreads();
            #pragma unroll
            for (int i = 0; i < 4; ++i) {
                const int xl = i * 8 + (tid >> 5);
                const int c = c0 + (tid & 31);
                if (c < 144)
                    out[(((size_t)b * PH + y + 1) * PH + x0 + xl + 1) * 144 + c] = T[tid & 31][xl];
            }
            __syncthreads();
        }
    }
}

// ---------------------------------------------------------------------------
// Pack x into gather-friendly fp16x4: xP[b][dg][pix].
// ---------------------------------------------------------------------------
__global__ __launch_bounds__(256) void pack_x_k(const float* __restrict__ x,
                                                sh4* __restrict__ xP) {
    int idx = blockIdx.x * 256 + threadIdx.x;
    if (idx >= BB * 16 * HWSZ) return;
    int b = idx / (16 * HWSZ);
    int rem = idx - b * 16 * HWSZ;
    int dg = rem / HWSZ, pix = rem - dg * HWSZ;
    const float* src = x + ((size_t)b * 64 + dg * 4) * HWSZ + pix;
    sh4 v;
    v[0] = (short)f16_rn(src[0]);
    v[1] = (short)f16_rn(src[HWSZ]);
    v[2] = (short)f16_rn(src[2 * HWSZ]);
    v[3] = (short)f16_rn(src[3 * HWSZ]);
    xP[idx] = v;
}

// ---------------------------------------------------------------------------
// conv0 (IC=144) LDS-STAGED, seg-major layout (proven r23).
// ---------------------------------------------------------------------------
__global__ __launch_bounds__(256, 2) void conv0_lds(
    const ushort* __restrict__ actIn, const ushort* __restrict__ wT,
    const float* __restrict__ bias, ushort* __restrict__ actOut)
{
    __shared__ ushort aS[18 * 3 * 66 * 8];   // 57,024 B

    const int tid = threadIdx.x;
    const int id  = blockIdx.x;
    const int orig = (id & 7) * 128 + (id >> 3);   // 1024 blocks, bijective
    const int xhalf = orig & 1;
    const int rid = orig >> 1;
    const int b = rid >> 7, y = rid & 127;
    const int xb = xhalf * 64;

    const int wave = tid >> 6, lane = tid & 63;
    const int wm = wave >> 1, wn = wave & 1;
    const int l31 = lane & 31, lhi = lane >> 5;

    for (int i = tid; i < 18 * 3 * 66; i += 256) {
        const int seg = i % 18;
        const int rp  = i / 18;
        const int px  = rp % 66;
        const int row = rp / 66;
        const ushort* src = actIn + (((size_t)b * PH + y + row) * PH + xb + px) * 144 + seg * 8;
        const int g = (seg * 3 + row) * 66 + px;
        *(short8*)&aS[g * 8] = *(const short8*)src;
    }
    __syncthreads();

    f32x16 acc = {};
    const ushort* wb = wT + (wm * 32 + l31) * 16 + lhi * 8;

    #pragma unroll
    for (int tap = 0; tap < 9; ++tap) {
        const int ky = tap / 3, kx = tap % 3;
        #pragma unroll
        for (int ks = 0; ks < 9; ++ks) {
            const int g = ((ks * 2 + lhi) * 3 + ky) * 66 + (wn * 32 + l31 + kx);
            const half8 af = __builtin_bit_cast(half8,
                *(const short8*)&aS[g * 8]);
            const half8 wf = __builtin_bit_cast(half8,
                *(const short8*)&wb[(size_t)(tap * 9 + ks) * 1024]);
            acc = __builtin_amdgcn_mfma_f32_32x32x16_f16(af, wf, acc, 0, 0, 0);
        }
    }

    const int oc = wm * 32 + l31;
    const float bi = bias[oc];
    ushort* ob = actOut + (((size_t)b * PH + y + 1) * PH + 1) * 64 + oc;
    #pragma unroll
    for (int r = 0; r < 16; ++r) {
        const int px = xb + wn * 32 + (r & 3) + 8 * (r >> 2) + 4 * lhi;
        float v = acc[r] + bi;
        v = v >= 0.f ? v : 0.1f * v;
        ob[(size_t)px * 64] = f16_rn(v);
    }
}

// ---------------------------------------------------------------------------
// conv1/2 (IC=64): LDS-STAGED act (r18-proven swizzle, ported r21).
// ---------------------------------------------------------------------------
__global__ __launch_bounds__(512, 2) void conv_lds(
    const ushort* __restrict__ actIn, const ushort* __restrict__ wT,
    const float* __restrict__ bias, ushort* __restrict__ actOut)
{
    __shared__ ushort aS[3 * 130 * 64];   // 49,920 B

    const int tid = threadIdx.x;
    const int id  = blockIdx.x;
    const int orig = (id & 7) * 64 + (id >> 3);    // 512 blocks, XCD-chunked
    const int b = orig >> 7, y = orig & 127;

    const int wave = tid >> 6, lane = tid & 63;
    const int wm = wave >> 2, wn = wave & 3;
    const int l31 = lane & 31, lhi = lane >> 5;

    for (int i = tid; i < 3 * 130 * 8; i += 512) {
        const int seg = i & 7;
        const int px  = (i >> 3) % 130;
        const int row = (i >> 3) / 130;
        const ushort* src = actIn + (((size_t)b * PH + y + row) * PH + px) * 64 + seg * 8;
        const int d16 = (row * 130 + px) * 8 + (seg ^ (px & 7));
        *(short8*)&aS[d16 * 8] = *(const short8*)src;
    }
    __syncthreads();

    f32x16 acc = {};
    const ushort* wb = wT + (wm * 32 + l31) * 16 + lhi * 8;

    #pragma unroll
    for (int tap = 0; tap < 9; ++tap) {
        const int ky = tap / 3, kx = tap % 3;
        #pragma unroll
        for (int ks = 0; ks < 4; ++ks) {
            const int lpx = wn * 32 + l31 + kx;              // 0..129
            const int idx16 = (ky * 130 + lpx) * 8 + ((ks * 2 + lhi) ^ (lpx & 7));
            const half8 af = __builtin_bit_cast(half8,
                *(const short8*)&aS[idx16 * 8]);
            const half8 wf = __builtin_bit_cast(half8,
                *(const short8*)&wb[(size_t)(tap * 4 + ks) * 1024]);
            acc = __builtin_amdgcn_mfma_f32_32x32x16_f16(af, wf, acc, 0, 0, 0);
        }
    }

    const int oc = wm * 32 + l31;
    const float bi = bias[oc];
    ushort* ob = actOut + (((size_t)b * PH + y + 1) * PH + 1) * 64 + oc;
    #pragma unroll
    for (int r = 0; r < 16; ++r) {
        const int px = wn * 32 + (r & 3) + 8 * (r >> 2) + 4 * lhi;
        float v = acc[r] + bi;
        v = v >= 0.f ? v : 0.1f * v;
        ob[(size_t)px * 64] = f16_rn(v);
    }
}

// ---------------------------------------------------------------------------
// conv3 channel-minor v6: LDS-STAGED acts with XOR swizzle (proven r18).
// ---------------------------------------------------------------------------
__global__ __launch_bounds__(512, 4) void conv3_cm(
    const ushort* __restrict__ actIn, const ushort* __restrict__ wT3,
    const float* __restrict__ bias, uint* __restrict__ offP,
    ushort* __restrict__ mskP, const float* __restrict__ flow)
{
    __shared__ ushort aS[3 * 66 * 64];   // 25,344 B

    const int tid = threadIdx.x;
    const int id  = blockIdx.x;
    const int orig = (id & 7) * 128 + (id >> 3);   // 1024 blocks, bijective
    const int xhalf = orig & 1;
    const int rid = orig >> 1;
    const int b = rid >> 7, y = rid & 127;
    const int xb = xhalf * 64;

    const int wave = tid >> 6, lane = tid & 63;
    const int l31 = lane & 31, lhi = lane >> 5;
    const int o0 = wave * 64;

    for (int i = tid; i < 3 * 66 * 8; i += 512) {
        const int seg = i & 7;
        const int px  = (i >> 3) % 66;
        const int row = (i >> 3) / 66;
        const ushort* src = actIn + (((size_t)b * PH + y + row) * PH + xb + px) * 64 + seg * 8;
        const int d16 = (row * 66 + px) * 8 + (seg ^ (px & 7));
        *(short8*)&aS[d16 * 8] = *(const short8*)src;
    }
    __syncthreads();

    f32x16 acc[2][2] = {};
    const ushort* wb = wT3 + (o0 + l31) * 16 + lhi * 8;

    #pragma unroll
    for (int tap = 0; tap < 9; ++tap) {
        const int ky = tap / 3, kx = tap % 3;
        #pragma unroll
        for (int ks = 0; ks < 4; ++ks) {
            const half8 af0 = __builtin_bit_cast(half8,
                *(const short8*)&wb[(size_t)(tap * 4 + ks) * 8192]);
            const half8 af1 = __builtin_bit_cast(half8,
                *(const short8*)&wb[(size_t)(tap * 4 + ks) * 8192 + 512]);
            #pragma unroll
            for (int pg = 0; pg < 2; ++pg) {
                const int lpx = pg * 32 + l31 + kx;
                const int idx16 = (ky * 66 + lpx) * 8 + ((ks * 2 + lhi) ^ (lpx & 7));
                const half8 bf = __builtin_bit_cast(half8,
                    *(const short8*)&aS[idx16 * 8]);
                acc[0][pg] = __builtin_amdgcn_mfma_f32_32x32x16_f16(af0, bf, acc[0][pg], 0, 0, 0);
                acc[1][pg] = __builtin_amdgcn_mfma_f32_32x32x16_f16(af1, bf, acc[1][pg], 0, 0, 0);
            }
        }
    }

    uint*   offb = offP + (size_t)b * 144 * HWSZ;
    ushort* mskb = mskP + (size_t)b * 144 * HWSZ;
    #pragma unroll
    for (int pg = 0; pg < 2; ++pg) {
        const int px = xb + pg * 32 + l31;
        const size_t pixb = (size_t)y * WW + px;
        const float fl0 = flow[((size_t)b * 2)     * HWSZ + pixb];
        const float fl1 = flow[((size_t)b * 2 + 1) * HWSZ + pixb];
        #pragma unroll
        for (int mg = 0; mg < 2; ++mg) {
            #pragma unroll
            for (int t = 0; t < 8; ++t) {
                const int r0 = 2 * t;
                const int oc = o0 + mg * 32 + (r0 & 3) + 8 * (r0 >> 2) + 4 * lhi;
                const float vy = acc[mg][pg][r0]     + bias[oc < 432 ? oc : 0];
                const float vx = acc[mg][pg][r0 + 1] + bias[oc < 431 ? oc + 1 : 0];
                if (oc < 288) {
                    const float ry = 10.f * fast_tanh(vy) + fl1;
                    const float rx = 10.f * fast_tanh(vx) + fl0;
                    offb[(size_t)(oc >> 1) * HWSZ + pixb] =
                        (uint)f16_rn(ry) | ((uint)f16_rn(rx) << 16);
                } else if (oc < 432) {
                    mskb[(size_t)(oc - 288) * HWSZ + pixb] = f16_rn(fast_sig(vy));
                    mskb[(size_t)(oc - 287) * HWSZ + pixb] = f16_rn(fast_sig(vx));
                }
            }
        }
    }
}

// ---------------------------------------------------------------------------
// MFMA deformable conv v14: v11 structure + PAIRED bilinear gathers.
// The 2 x-adjacent corners are contiguous 8B cells -> ONE 16B load at
// cxb=clamp(xi,0,126) + lo/hi selects (border cases: xi=-1 -> c01=lo,
// f00=0; xi=127 -> c00=hi, f01=0; else lo/hi). Gathers/sample 4 -> 2;
// the TA unit (~80% busy on gathers per cyc model) is the deform wall.
// ---------------------------------------------------------------------------
__global__ __launch_bounds__(512, 4) void deform_v14(
    const sh4* __restrict__ xP, const uint* __restrict__ offP,
    const ushort* __restrict__ mskP, const ushort* __restrict__ wdfh,
    const float* __restrict__ bias, float* __restrict__ outp)
{
    __shared__ float red[2][2][64][33];   // 33,792 B

    const int tid = threadIdx.x;
    const int id  = blockIdx.x;
    const int orig = (id & 7) * 128 + (id >> 3);   // 1024 blocks, bijective
    const int x0 = (orig & 1) * 64;
    const int rl = orig >> 1;
    const int y = rl & 127, b = rl >> 7;

    const int wave = tid >> 6, lane = tid & 63;
    const int l31 = lane & 31, lhi = lane >> 5;
    const int pxh = wave >> 2;          // which 32-px half
    const int w4  = wave & 3;           // K-quadrant index
    const int k9h = w4 >> 1;
    const int hv  = w4 & 1;

    const int xp  = x0 + pxh * 32 + l31;
    const int pix = y * WW + xp;
    const uint*   offb = offP + (size_t)b * 144 * HWSZ;
    const ushort* mskb = mskP + (size_t)b * 144 * HWSZ;
    const float fy = (float)y, fx = (float)xp;

    f32x16 acc[2] = {};

    const int k9lo = k9h ? 5 : 0;
    const int k9hi = k9h ? 9 : 5;
    for (int k9 = k9lo; k9 < k9hi; ++k9) {
        const float kyf = (float)(k9 / 3 - 1);
        const float kxf = (float)(k9 % 3 - 1);
        #pragma unroll
        for (int ks = 0; ks < 2; ++ks) {
            short8 bfs;
            #pragma unroll
            for (int d2 = 0; d2 < 2; ++d2) {
                const int dg = hv * 8 + ks * 4 + lhi * 2 + d2;
                const int m  = dg * 9 + k9;
                const uint u = offb[(size_t)m * HWSZ + pix];
                const float dy = f16_f((ushort)(u & 0xffffu));
                const float dx = f16_f((ushort)(u >> 16));
                const float mk = f16_f(mskb[(size_t)m * HWSZ + pix]);
                const float py = dy + kyf + fy;
                const float px = dx + kxf + fx;
                const float y0f = floorf(py), x0f = floorf(px);
                const float ly = py - y0f, lx = px - x0f;
                const int yi = (int)y0f, xi = (int)x0f;
                const float w00 = (1.f - ly) * (1.f - lx), w01 = (1.f - ly) * lx;
                const float w10 = ly * (1.f - lx),         w11 = ly * lx;
                const bool vy0 = (unsigned)yi < (unsigned)HH, vy1 = (unsigned)(yi + 1) < (unsigned)HH;
                const bool vx0 = (unsigned)xi < (unsigned)WW, vx1 = (unsigned)(xi + 1) < (unsigned)WW;
                const float f00 = (vy0 && vx0) ? w00 * mk : 0.f;
                const float f01 = (vy0 && vx1) ? w01 * mk : 0.f;
                const float f10 = (vy1 && vx0) ? w10 * mk : 0.f;
                const float f11 = (vy1 && vx1) ? w11 * mk : 0.f;
                const int cy0 = min(max(yi, 0), HH - 1), cy1 = min(max(yi + 1, 0), HH - 1);
                const int cxb = min(max(xi, 0), WW - 2);
                const sh4* xg = xP + (size_t)(b * 16 + dg) * HWSZ;
                // paired 16B gathers: cols {cxb, cxb+1} of rows cy0, cy1
                const short8u p0 = *(const short8u*)&xg[cy0 * WW + cxb];
                const short8u p1 = *(const short8u*)&xg[cy1 * WW + cxb];
                const sh4 p0lo = {p0[0], p0[1], p0[2], p0[3]};
                const sh4 p0hi = {p0[4], p0[5], p0[6], p0[7]};
                const sh4 p1lo = {p1[0], p1[1], p1[2], p1[3]};
                const sh4 p1hi = {p1[4], p1[5], p1[6], p1[7]};
                const bool sel00 = (xi >= WW - 1);   // c00 = hi when xi==127
                const bool sel01 = (xi < 0);         // c01 = lo when xi==-1
                const sh4 c00 = sel00 ? p0hi : p0lo;
                const sh4 c01 = sel01 ? p0lo : p0hi;
                const sh4 c10 = sel00 ? p1hi : p1lo;
                const sh4 c11 = sel01 ? p1lo : p1hi;
                #pragma unroll
                for (int n = 0; n < 4; ++n) {
                    const float s = f00 * f16_f((ushort)c00[n]) + f01 * f16_f((ushort)c01[n])
                                  + f10 * f16_f((ushort)c10[n]) + f11 * f16_f((ushort)c11[n]);
                    bfs[d2 * 4 + n] = (short)f16_rn(s);
                }
            }
            const half8 bf = __builtin_bit_cast(half8, bfs);
            const size_t abase = (size_t)((k9 * 2 + hv) * 2 + ks) * 1024 + l31 * 16 + lhi * 8;
            #pragma unroll
            for (int mg = 0; mg < 2; ++mg) {
                const half8 ah = __builtin_bit_cast(half8, *(const short8*)&wdfh[abase + mg * 512]);
                acc[mg] = __builtin_amdgcn_mfma_f32_32x32x16_f16(ah, bf, acc[mg], 0, 0, 0);
            }
        }
    }

    // ---- per-pxh 3-phase reduction across the 4 K-quadrant waves ----
    if (w4 >= 2) {
        #pragma unroll
        for (int mg = 0; mg < 2; ++mg)
            #pragma unroll
            for (int r = 0; r < 16; ++r)
                red[pxh][w4 - 2][lane][mg * 16 + r] = acc[mg][r];
    }
    __syncthreads();
    if (w4 < 2) {
        #pragma unroll
        for (int mg = 0; mg < 2; ++mg)
            #pragma unroll
            for (int r = 0; r < 16; ++r)
                acc[mg][r] += red[pxh][w4][lane][mg * 16 + r];
    }
    __syncthreads();
    if (w4 == 1) {
        #pragma unroll
        for (int mg = 0; mg < 2; ++mg)
            #pragma unroll
            for (int r = 0; r < 16; ++r)
                red[pxh][0][lane][mg * 16 + r] = acc[mg][r];
    }
    __syncthreads();
    if (w4 == 0) {
        #pragma unroll
        for (int mg = 0; mg < 2; ++mg)
            #pragma unroll
            for (int r = 0; r < 16; ++r) {
                const int oc = mg * 32 + (r & 3) + 8 * (r >> 2) + 4 * lhi;
                const float v = acc[mg][r] + red[pxh][0][lane][mg * 16 + r] + bias[oc];
                outp[(((size_t)b * 64 + oc) * HH + y) * WW + xp] = v;
            }
    }
}

// ---------------------------------------------------------------------------
extern "C" void kernel_launch(void* const* d_in, const int* in_sizes, int n_in,
                              void* d_out, int out_size, void* d_ws, size_t ws_size,
                              hipStream_t stream) {
    const float* x    = (const float*)d_in[0];
    const float* xfw  = (const float*)d_in[1];
    const float* xcur = (const float*)d_in[2];
    const float* flow = (const float*)d_in[3];
    const float* w0   = (const float*)d_in[4];
    const float* b0   = (const float*)d_in[5];
    const float* w1   = (const float*)d_in[6];
    const float* b1   = (const float*)d_in[7];
    const float* w2   = (const float*)d_in[8];
    const float* b2   = (const float*)d_in[9];
    const float* w3   = (const float*)d_in[10];
    const float* b3   = (const float*)d_in[11];
    const float* wdcn = (const float*)d_in[12];
    const float* bdcn = (const float*)d_in[13];
    float* out = (float*)d_out;

    // workspace layout (all 16B-aligned):
    char* p = (char*)d_ws;
    uint*   offP    = (uint*)p;                         p += (size_t)BB * 144 * HWSZ * 4;   // 37.7MB
    ushort* mskP    = (ushort*)p;                       p += (size_t)BB * 144 * HWSZ * 2;   // 18.9MB
    ushort* h0A     = (ushort*)p;                       p += (size_t)BB * PH * PH * 64 * 2; // 8.65MB
    ushort* h1A     = (ushort*)p;                       p += (size_t)BB * PH * PH * 64 * 2; // 8.65MB
    ushort* concatA = (ushort*)p;                       p += (size_t)BB * PH * PH * 144 * 2;// 19.5MB
    sh4*    xPh     = (sh4*)p;                          p += (size_t)BB * 16 * HWSZ * 8;    // 8.4MB
    ushort* wdh = (ushort*)p;                           p += 64 * 576 * 2;
    ushort* w0T = (ushort*)p;                           p += 9 * 9 * 64 * 16 * 2;
    ushort* w1T = (ushort*)p;                           p += 9 * 4 * 64 * 16 * 2;
    ushort* w2T = (ushort*)p;                           p += 9 * 4 * 64 * 16 * 2;
    ushort* w3T = (ushort*)p;                           p += 36 * 512 * 16 * 2;
    ushort* h2A = h0A;   // conv2 output reuses h0A (h0A dead after conv1)

    // zero only the 1-px borders (interiors fully written by producers)
    zero_border<<<dim3((BB * 4 * PH * 144 + 255) / 256), dim3(256), 0, stream>>>(concatA, 144);
    zero_border<<<dim3((BB * 4 * PH * 64 + 255) / 256),  dim3(256), 0, stream>>>(h0A, 64);
    zero_border<<<dim3((BB * 4 * PH * 64 + 255) / 256),  dim3(256), 0, stream>>>(h1A, 64);

    prep_wcm<<<dim3((9 * 9 * 64 * 16 + 255) / 256), dim3(256), 0, stream>>>(w0, w0T, 130, 144);
    prep_wcm<<<dim3((9 * 4 * 64 * 16 + 255) / 256), dim3(256), 0, stream>>>(w1, w1T, 64, 64);
    prep_wcm<<<dim3((9 * 4 * 64 * 16 + 255) / 256), dim3(256), 0, stream>>>(w2, w2T, 64, 64);
    prep_w3cm<<<dim3((36 * 512 * 16 + 255) / 256), dim3(256), 0, stream>>>(w3, w3T);
    prep_wdf_k<<<dim3((64 * 576 + 255) / 256), dim3(256), 0, stream>>>(wdcn, wdh);
    cvt_cm<<<dim3(BB * HH), dim3(256), 0, stream>>>(xfw, xcur, flow, concatA);
    pack_x_k<<<dim3((BB * 16 * HWSZ + 255) / 256), dim3(256), 0, stream>>>(x, xPh);

    conv0_lds<<<dim3(BB * HH * 2), dim3(256), 0, stream>>>(concatA, w0T, b0, h0A);
    conv_lds<<<dim3(BB * HH), dim3(512), 0, stream>>>(h0A, w1T, b1, h1A);
    conv_lds<<<dim3(BB * HH), dim3(512), 0, stream>>>(h1A, w2T, b2, h2A);
    conv3_cm<<<dim3(BB * HH * 2), dim3(512), 0, stream>>>(h2A, w3T, b3, offP, mskP, flow);

    deform_v14<<<dim3(1024), dim3(512), 0, stream>>>(xPh, offP, mskP, wdh, bdcn, out);
}